// Round 12
// baseline (268.196 us; speedup 1.0000x reference)
//
#include <hip/hip_runtime.h>
#include <math.h>

// Problem constants (fixed by setup_inputs)
#define NROWS 32768   // 32 * 32 * 32
#define DIMS  256
#define KCODES 1024

typedef __attribute__((ext_vector_type(8))) short short8;   // 8 bf16 = 4 VGPRs
typedef __attribute__((ext_vector_type(4))) float f32x4;    // MFMA C/D & stores

// word-level XOR swizzle for the f32 x-bounce tile
#define SWZW(hw) ((((hw) >> 2) & 7) << 2)

// ws layout (float offsets)
static const size_t OFF_WB     = 8388608;                // [1024][256] bf16, MFMA-fragment tile order
static const size_t OFF_WNORM  = OFF_WB + 131072;        // [1024] f32
static const size_t OFF_ENCSUM = OFF_WNORM + 1024;       // [1024]
static const size_t OFF_LOSSP  = OFF_ENCSUM + 1024;      // [2048 used]
static const size_t OFF_WND    = OFF_LOSSP + 8192;       // [1024] f64 (2048 floats), 8B aligned

// out layout (float offsets): loss | quantized NCHW | perplexity | encodings
static const size_t OUT_Q    = 1;
static const size_t OUT_PERP = 8388609;
static const size_t OUT_ENC  = 8388610;

__device__ inline unsigned short f2bf(float f) {
    unsigned int u = __float_as_uint(f);
    unsigned int r = u + 0x7FFFu + ((u >> 16) & 1u);   // RNE
    return (unsigned short)(r >> 16);
}

// pack distance (fp32, low 10 mantissa bits cleared) with 10-bit code index.
__device__ inline float packdi(float d, int code) {
    return __uint_as_float((__float_as_uint(d) & 0xFFFFFC00u) | (unsigned)code);
}

// async global->LDS copy, 16B per lane (wave-uniform LDS base + lane*16)
__device__ __forceinline__ void gl_lds16(const void* gsrc, void* ldst) {
    typedef const __attribute__((address_space(1))) unsigned int GU;
    typedef __attribute__((address_space(3))) unsigned int LU;
    __builtin_amdgcn_global_load_lds((GU*)gsrc, (LU*)ldst, 16, 0, 0);
}

// ---------------- W prep: bf16 fragment-order layout + wnorm (f32+f64) ----
__global__ __launch_bounds__(256) void wprep(const float* __restrict__ Wm,
                                             unsigned short* __restrict__ Wb,
                                             float* __restrict__ wnorm,
                                             double* __restrict__ wnormd,
                                             float* __restrict__ enc_sum)
{
    const int r = blockIdx.x * 4 + (threadIdx.x >> 6);
    const int lane = threadIdx.x & 63;
    float4 v = ((const float4*)(Wm + (size_t)r * 256))[lane];
    ushort4 o;
    o.x = f2bf(v.x); o.y = f2bf(v.y); o.z = f2bf(v.z); o.w = f2bf(v.w);
    const int d0 = lane * 4;
    const int kk = d0 >> 5, quad = (d0 >> 3) & 3, jb = d0 & 7;
    const int tt = r >> 4, col = r & 15;
    const size_t idx = (size_t)tt * 4096 + (size_t)((kk * 4 + quad) * 16 + col) * 8 + jb;
    *(ushort4*)(Wb + idx) = o;
    double s = (double)v.x*(double)v.x + (double)v.y*(double)v.y
             + (double)v.z*(double)v.z + (double)v.w*(double)v.w;
    #pragma unroll
    for (int off = 32; off > 0; off >>= 1) s += __shfl_down(s, off);
    if (lane == 0) { wnormd[r] = s; wnorm[r] = (float)s; }
    if (blockIdx.x == 0) {
        #pragma unroll
        for (int q = 0; q < 4; ++q) enc_sum[threadIdx.x * 4 + q] = 0.0f;
    }
}

// ---------------- fused MFMA GEMM + top-k + fp64 refine + enc + quantize + loss ----
// 128 thr = 2 waves, 16 rows/block, grid 2048, LDS 36 KB -> 4 blocks/CU.
// WAVE-UNIQUE CODES (R12): wave h owns code-half h (codes h*512..) outright —
// stages AND reads only its own 8KB tile/iter. Loop ds_read_b128 per row
// halves vs the g-split layout (no duplicate B reads); barriers per row halve.
// Mappings:
//   MFMA:   wave h; lane: col (code), quad; A rows = col (rows 0..15)
//   refine: row = t>>3 (0..15), q8 = t&7; thread owns dims c*32 + q8*4 + k.
// x ingestion: two-pass coalesced f32 LDS bounce (SWZW swizzle).
// Main loop (32 iters): dbuf 2x16KB via global_load_lds; split 4+4 MFMA
// chains; med3 exact top-3 insert; in-loop enc half-row zero-streaming.
// Quantize: single pass, qtile [16][257] (stride mod 32 = 1, ~2-way free).
__global__ __launch_bounds__(128, 2) void gemm_topk_quant(
    const float* __restrict__ x, const unsigned short* __restrict__ Wb,
    const float* __restrict__ wnorm, const double* __restrict__ wnd,
    const float* __restrict__ Wm,
    float* __restrict__ enc_sum,
    float* __restrict__ enc,
    float* __restrict__ outq, float* __restrict__ loss_part)
{
    __shared__ __align__(16) char lds[36864];
    // loop: buf0 = lds[0,16K), buf1 = lds[16K,32K); wnLds @ 32K (4 KB)
    // post-loop aliases (phases separated by barriers):
    float*  sCd   = (float*)lds;                 // [96][19] f32 = 7296 B (dump->merge)
    int*    mIdx  = (int*)(lds + 7424);          // [128] -> 7936
    double* rd    = (double*)(lds + 7936);       // [128] f64 -> 8960
    double* rnr   = (double*)(lds + 8960);       // [16] f64 -> 9088
    float*  qtile = (float*)lds;                 // [16][257] f32 = 16448 B (epilogue)
    int*    s0    = (int*)(lds + 16640);         // [16]
    int*    s1    = (int*)(lds + 16704);         // [16]
    float*  sw0   = (float*)(lds + 16768);       // [16]
    float*  sw1   = (float*)(lds + 16832);       // [16]
    double* sredd = (double*)(lds + 16896);      // [2]
    float*  xbounce = (float*)(lds + 16384);     // [16][128] f32 = 8 KB, pre-loop (buf1)
    float*  wnLds = (float*)(lds + 32768);       // [1024] f32 (loop only)

    const int t    = threadIdx.x;
    const int h    = t >> 6;          // wave = code half
    const int lane = t & 63;
    const int col  = lane & 15;
    const int quad = lane >> 4;
    const int r0   = blockIdx.x * 16;
    const int b    = r0 >> 10;
    const int hw0  = r0 & 1023;
    const float* xblk = x + (size_t)b * 262144 + hw0;   // + d*1024 + hw_local

    const int row = t >> 3;   // refine/epilogue row (hw local), 0..15
    const int q8  = t & 7;    // dim-slice

    // ---- issue prologue B staging (cc=0 -> buf0) + wnorm -> wnLds first ----
    const char* wb_bytes = (const char*)Wb;
    {
        const char* src = wb_bytes + (size_t)(h * 32) * 8192;
        char* dstl = lds + h * 8192;
        #pragma unroll
        for (int q = 0; q < 8; ++q)
            gl_lds16(src + q * 1024 + lane * 16, dstl + q * 1024);
        #pragma unroll
        for (int q = 0; q < 2; ++q)
            gl_lds16((const char*)wnorm + h * 2048 + q * 1024 + lane * 16,
                     (char*)wnLds + h * 2048 + q * 1024);
    }

    // ---- x ingestion: two-pass coalesced bounce through LDS ----
    float xs[32];
    short8 af[8];
    const int hwq   = t & 3;       // hw chunk (load mapping), 4 chunks x 4 hw
    const int dbase = t >> 2;      // 0..31   (load mapping)
    #pragma unroll
    for (int h2 = 0; h2 < 2; ++h2) {
        float4 xv0, xv1, xv2, xv3;
        {
            const float* xp = xblk + hwq * 4;
            xv0 = *(const float4*)(xp + (size_t)(h2 * 128 +  0 + dbase) * 1024);
            xv1 = *(const float4*)(xp + (size_t)(h2 * 128 + 32 + dbase) * 1024);
            xv2 = *(const float4*)(xp + (size_t)(h2 * 128 + 64 + dbase) * 1024);
            xv3 = *(const float4*)(xp + (size_t)(h2 * 128 + 96 + dbase) * 1024);
        }
        if (h2) __syncthreads();   // pass-0 readers done before overwrite
        #pragma unroll
        for (int rr = 0; rr < 4; ++rr) {
            const float4 xv = (rr == 0) ? xv0 : (rr == 1) ? xv1 : (rr == 2) ? xv2 : xv3;
            const int dloc = rr * 32 + dbase;
            #pragma unroll
            for (int j = 0; j < 4; ++j) {
                const int hw = hwq * 4 + j;
                const float vj = (j == 0) ? xv.x : (j == 1) ? xv.y : (j == 2) ? xv.z : xv.w;
                xbounce[(hw * 128 + dloc) ^ SWZW(hw)] = vj;
            }
        }
        __syncthreads();
        // xs: 4 b128 reads (dims c*32 + q8*4 .. +3)
        #pragma unroll
        for (int c2 = 0; c2 < 4; ++c2) {
            const int w = (row * 128 + c2 * 32 + q8 * 4) ^ SWZW(row);
            f32x4 v = *(const f32x4*)(xbounce + w);
            xs[(h2 * 4 + c2) * 4 + 0] = v.x;
            xs[(h2 * 4 + c2) * 4 + 1] = v.y;
            xs[(h2 * 4 + c2) * 4 + 2] = v.z;
            xs[(h2 * 4 + c2) * 4 + 3] = v.w;
        }
        // af: direct f32 -> bf16 fragments (A rows = col, 0..15)
        #pragma unroll
        for (int kk2 = 0; kk2 < 4; ++kk2) {
            const int dloc = kk2 * 32 + quad * 8;
            const int wA = (col * 128 + dloc) ^ SWZW(col);
            const int wB = (col * 128 + dloc + 4) ^ SWZW(col);
            f32x4 u = *(const f32x4*)(xbounce + wA);
            f32x4 v = *(const f32x4*)(xbounce + wB);
            short8 f;
            f[0] = (short)f2bf(u.x); f[1] = (short)f2bf(u.y);
            f[2] = (short)f2bf(u.z); f[3] = (short)f2bf(u.w);
            f[4] = (short)f2bf(v.x); f[5] = (short)f2bf(v.y);
            f[6] = (short)f2bf(v.z); f[7] = (short)f2bf(v.w);
            af[h2 * 4 + kk2] = f;
        }
    }
    __syncthreads();   // pass-1 reads done; buf0+wnLds staged; cc=0 may write buf1

    float m0[4], m1[4], m2[4];
    #pragma unroll
    for (int r = 0; r < 4; ++r) { m0[r] = 3.4e38f; m1[r] = 3.4e38f; m2[r] = 3.4e38f; }

    const f32x4 zero4 = {0.f, 0.f, 0.f, 0.f};
    for (int cc = 0; cc < 32; ++cc) {
        if (cc < 31) {
            const char* src = wb_bytes + (size_t)(h * 32 + cc + 1) * 8192;
            char* dstl = lds + ((cc + 1) & 1) * 16384 + h * 8192;
            #pragma unroll
            for (int q = 0; q < 8; ++q)
                gl_lds16(src + q * 1024 + lane * 16, dstl + q * 1024);
        }
        // zero-stream half an encodings row per iteration (coalesced 2 KB)
        *(f32x4*)(enc + (size_t)(r0 + (cc >> 1)) * KCODES + (cc & 1) * 512 + t * 4) = zero4;

        const char* bb = lds + (cc & 1) * 16384 + h * 8192;
        f32x4 acc_a = {0.f, 0.f, 0.f, 0.f};
        f32x4 acc_b = {0.f, 0.f, 0.f, 0.f};
        #pragma unroll
        for (int kk = 0; kk < 4; ++kk) {
            short8 b0 = *(const short8*)(bb + kk * 1024 + lane * 16);
            short8 b1 = *(const short8*)(bb + (kk + 4) * 1024 + lane * 16);
            acc_a = __builtin_amdgcn_mfma_f32_16x16x32_bf16(af[kk], b0, acc_a, 0, 0, 0);
            acc_b = __builtin_amdgcn_mfma_f32_16x16x32_bf16(af[kk + 4], b1, acc_b, 0, 0, 0);
        }
        const int code0 = h * 512 + cc * 16 + col;
        const float wn0 = wnLds[code0];
        #pragma unroll
        for (int r = 0; r < 4; ++r) {
            float pv0 = packdi(fmaf(-2.0f, acc_a[r] + acc_b[r], wn0), code0);
            // exact sorted-3 insert via med3 (3 ops)
            m2[r] = __builtin_amdgcn_fmed3f(m1[r], m2[r], pv0);
            m1[r] = __builtin_amdgcn_fmed3f(m0[r], m1[r], pv0);
            m0[r] = fminf(m0[r], pv0);
        }
        __syncthreads();   // staged data for cc+1 visible; buf[cc&1] reads done
    }

    // ---- dump per-lane candidates, transposed layout [96 slots][19 rows] ----
    #pragma unroll
    for (int r = 0; r < 4; ++r) {
        const int rl = quad * 4 + r;
        const int s  = h * 48 + col * 3;
        sCd[(s + 0) * 19 + rl] = m0[r];
        sCd[(s + 1) * 19 + rl] = m1[r];
        sCd[(s + 2) * 19 + rl] = m2[r];
    }
    __syncthreads();

    // ---- parallel exact top-8 merge: 8 threads/row, 12 slots each ----
    {
        float a0 = 3.4e38f, a1 = 3.4e38f, a2 = 3.4e38f, a3 = 3.4e38f,
              a4 = 3.4e38f, a5 = 3.4e38f, a6 = 3.4e38f, a7 = 3.4e38f;
        #pragma unroll
        for (int i = 0; i < 12; ++i) {
            float d = sCd[(q8 * 12 + i) * 19 + row];
            if (d < a7) {
                a7 = d; float tf;
                if (a7 < a6) { tf = a7; a7 = a6; a6 = tf; }
                if (a6 < a5) { tf = a6; a6 = a5; a5 = tf; }
                if (a5 < a4) { tf = a5; a5 = a4; a4 = tf; }
                if (a4 < a3) { tf = a4; a4 = a3; a3 = tf; }
                if (a3 < a2) { tf = a3; a3 = a2; a2 = tf; }
                if (a2 < a1) { tf = a2; a2 = a1; a1 = tf; }
                if (a1 < a0) { tf = a1; a1 = a0; a0 = tf; }
            }
        }
        // 8 rounds: global min of the 8 heads (values unique via packed code bits)
        float sel = 3.4e38f;
        #pragma unroll
        for (int q = 0; q < 8; ++q) {
            float m = a0;
            m = fminf(m, __shfl_xor(m, 1));
            m = fminf(m, __shfl_xor(m, 2));
            m = fminf(m, __shfl_xor(m, 4));
            if (q8 == q) sel = m;
            if (a0 == m) { a0 = a1; a1 = a2; a2 = a3; a3 = a4;
                           a4 = a5; a5 = a6; a6 = a7; a7 = 3.4e38f; }
        }
        mIdx[row * 8 + q8] = (int)(__float_as_uint(sel) & 1023u);
    }
    __syncthreads();

    // ---- fp64 refine from xs regs: coalesced 128B W reads per row-octet ----
    {
        int cd[8];
        #pragma unroll
        for (int c8 = 0; c8 < 8; ++c8) cd[c8] = mIdx[row * 8 + c8];
        double dot[8];
        #pragma unroll
        for (int c8 = 0; c8 < 8; ++c8) dot[c8] = 0.0;
        double rn = 0.0;
        #pragma unroll
        for (int c = 0; c < 8; ++c) {
            const int d0 = c * 32 + q8 * 4;
            const double x0 = (double)xs[c * 4 + 0];
            const double x1 = (double)xs[c * 4 + 1];
            const double x2 = (double)xs[c * 4 + 2];
            const double x3 = (double)xs[c * 4 + 3];
            rn += x0*x0 + x1*x1 + x2*x2 + x3*x3;
            #pragma unroll
            for (int c8 = 0; c8 < 8; ++c8) {
                const float4 wv = *(const float4*)(Wm + (size_t)cd[c8] * 256 + d0);
                dot[c8] += x0 * (double)wv.x + x1 * (double)wv.y
                         + x2 * (double)wv.z + x3 * (double)wv.w;
            }
        }
        #pragma unroll
        for (int m = 1; m < 8; m <<= 1) {
            #pragma unroll
            for (int c8 = 0; c8 < 8; ++c8) dot[c8] += __shfl_xor(dot[c8], m);
            rn += __shfl_xor(rn, m);
        }
        // static select of this thread's candidate (avoid dynamic reg indexing)
        int myc = 0; double mydot = 0.0;
        #pragma unroll
        for (int c8 = 0; c8 < 8; ++c8)
            if (q8 == c8) { myc = cd[c8]; mydot = dot[c8]; }
        rd[row * 8 + q8] = wnd[myc] - 2.0 * mydot;
        if (q8 == 0) rnr[row] = rn;
    }
    __syncthreads();

    // ---- final per-row top-2 (exact), weights + enc patch stores ----
    if (t < 16) {
        double rn = rnr[t];
        double d0 = 1e300, d1 = 1e300; int b0 = 1 << 30, b1 = 1 << 30;
        #pragma unroll
        for (int q = 0; q < 8; ++q) {
            double d = rd[t * 8 + q];
            int    c = mIdx[t * 8 + q];
            if (d < d0 || (d == d0 && c < b0)) { d1 = d0; b1 = b0; d0 = d; b0 = c; }
            else if (d < d1 || (d == d1 && c < b1)) { d1 = d; b1 = c; }
        }
        double D0 = rn + d0;
        double D1 = rn + d1;
        double inv0 = 1.0 / D0, inv1 = 1.0 / D1;
        double nrm = sqrt(inv0 * inv0 + inv1 * inv1);
        if (nrm < 1e-12) nrm = 1e-12;
        float w0 = (float)(inv0 / nrm);
        float w1 = (float)(inv1 / nrm);
        s0[t] = b0; s1[t] = b1; sw0[t] = w0; sw1[t] = w1;
        atomicAdd(&enc_sum[b0], w0);
        atomicAdd(&enc_sum[b1], w1);
        // patch the two weights into the pre-zeroed encodings row
        // (zeros issued in-loop, drained by the interleaving barriers).
        enc[(size_t)(r0 + t) * KCODES + b0] = w0;
        enc[(size_t)(r0 + t) * KCODES + b1] = w1;
    }
    __syncthreads();

    // ---- quantize + loss (from xs) + NCHW write, single full-width pass ----
    double ls = 0.0;
    {
        const int   cA = s0[row], cB = s1[row];
        const float w0 = sw0[row], w1 = sw1[row];
        #pragma unroll
        for (int c = 0; c < 8; ++c) {
            const int dg = c * 32 + q8 * 4;
            const float4 a  = *(const float4*)(Wm + (size_t)cA * 256 + dg);
            const float4 bv = *(const float4*)(Wm + (size_t)cB * 256 + dg);
            float q0 = w0 * a.x + w1 * bv.x;
            float q1 = w0 * a.y + w1 * bv.y;
            float q2 = w0 * a.z + w1 * bv.z;
            float q3 = w0 * a.w + w1 * bv.w;
            float e0 = q0 - xs[c * 4 + 0];
            float e1 = q1 - xs[c * 4 + 1];
            float e2 = q2 - xs[c * 4 + 2];
            float e3 = q3 - xs[c * 4 + 3];
            ls += (double)(e0*e0 + e1*e1 + e2*e2 + e3*e3);
            float* qp = qtile + row * 257 + dg;   // scalar stores: ~2-way, free
            qp[0] = q0; qp[1] = q1; qp[2] = q2; qp[3] = q3;
        }
    }
    __syncthreads();
    #pragma unroll
    for (int p = 0; p < 8; ++p) {
        const int task = p * 128 + t;
        const int cl   = task >> 2;       // channel 0..255
        const int hq   = task & 3;        // hw quad 0..3
        f32x4 v;
        v.x = qtile[(hq * 4 + 0) * 257 + cl];
        v.y = qtile[(hq * 4 + 1) * 257 + cl];
        v.z = qtile[(hq * 4 + 2) * 257 + cl];
        v.w = qtile[(hq * 4 + 3) * 257 + cl];
        *(f32x4*)(outq + ((size_t)(b * 256 + cl)) * 1024 + hw0 + hq * 4) = v;
    }

    // ---- block loss partial ----
    #pragma unroll
    for (int off = 32; off > 0; off >>= 1) ls += __shfl_down(ls, off);
    if (lane == 0) sredd[h] = ls;
    __syncthreads();
    if (t == 0) loss_part[blockIdx.x] = (float)(sredd[0] + sredd[1]);
}

// ---------------- finalize: loss + perplexity ----------------
__global__ __launch_bounds__(256) void finalize_k(const float* __restrict__ enc_sum,
                                                  const float* __restrict__ loss_part,
                                                  float* __restrict__ out)
{
    __shared__ double sh[256];
    const int t = threadIdx.x;
    double ls = 0.0;
    for (int i = t; i < 2048; i += 256) ls += (double)loss_part[i];
    sh[t] = ls; __syncthreads();
    for (int s = 128; s > 0; s >>= 1) { if (t < s) sh[t] += sh[t + s]; __syncthreads(); }
    double loss_sum = sh[0];
    __syncthreads();
    double ps = 0.0;
    for (int k = t; k < KCODES; k += 256) {
        double p = (double)enc_sum[k] / (double)NROWS;
        ps += p * log(p + 1e-10);
    }
    sh[t] = ps; __syncthreads();
    for (int s = 128; s > 0; s >>= 1) { if (t < s) sh[t] += sh[t + s]; __syncthreads(); }
    if (t == 0) {
        out[0]        = (float)(1.25 * loss_sum / 8388608.0);
        out[OUT_PERP] = (float)exp(-sh[0]);
    }
}

extern "C" void kernel_launch(void* const* d_in, const int* in_sizes, int n_in,
                              void* d_out, int out_size, void* d_ws, size_t ws_size,
                              hipStream_t stream)
{
    const float* x  = (const float*)d_in[0];
    const float* Wm = (const float*)d_in[1];
    float* out = (float*)d_out;
    float* ws  = (float*)d_ws;

    unsigned short* Wb      = (unsigned short*)(ws + OFF_WB);
    float*          wnorm   = ws + OFF_WNORM;
    float*          enc_sum = ws + OFF_ENCSUM;
    float*          loss_p  = ws + OFF_LOSSP;
    double*         wnd     = (double*)(ws + OFF_WND);

    wprep<<<KCODES / 4, 256, 0, stream>>>(Wm, Wb, wnorm, wnd, enc_sum);
    gemm_topk_quant<<<NROWS / 16, 128, 0, stream>>>(x, Wb, wnorm, wnd, Wm, enc_sum,
                                                    out + OUT_ENC, out + OUT_Q, loss_p);
    finalize_k<<<1, 256, 0, stream>>>(enc_sum, loss_p, out);
}

// Round 13
// 237.346 us; speedup vs baseline: 1.1300x; 1.1300x over previous
//
#include <hip/hip_runtime.h>
#include <math.h>

// Problem constants (fixed by setup_inputs)
#define NROWS 32768   // 32 * 32 * 32
#define DIMS  256
#define KCODES 1024

typedef __attribute__((ext_vector_type(8))) short short8;   // 8 bf16 = 4 VGPRs
typedef __attribute__((ext_vector_type(4))) float f32x4;    // MFMA C/D & stores

// word-level XOR swizzle for the f32 x-bounce tile: carries ALL of hw>>2
// (the load-lane hw-chunk id) into bank bits 2-4. Write side = 2-way (free);
// xs/af b128 reads stay at the 8-lane/16B-group floor.
#define SWZW(hw) ((((hw) >> 2) & 7) << 2)

// ws layout (float offsets)
static const size_t OFF_WB     = 8388608;                // [1024][256] bf16, MFMA-fragment tile order
static const size_t OFF_WNORM  = OFF_WB + 131072;        // [1024] f32
static const size_t OFF_ENCSUM = OFF_WNORM + 1024;       // [1024]
static const size_t OFF_LOSSP  = OFF_ENCSUM + 1024;      // [1024 used]
static const size_t OFF_WND    = OFF_LOSSP + 8192;       // [1024] f64 (2048 floats), 8B aligned

// out layout (float offsets): loss | quantized NCHW | perplexity | encodings
static const size_t OUT_Q    = 1;
static const size_t OUT_PERP = 8388609;
static const size_t OUT_ENC  = 8388610;

__device__ inline unsigned short f2bf(float f) {
    unsigned int u = __float_as_uint(f);
    unsigned int r = u + 0x7FFFu + ((u >> 16) & 1u);   // RNE
    return (unsigned short)(r >> 16);
}

// pack distance (fp32, low 10 mantissa bits cleared) with 10-bit code index.
__device__ inline float packdi(float d, int code) {
    return __uint_as_float((__float_as_uint(d) & 0xFFFFFC00u) | (unsigned)code);
}

// async global->LDS copy, 16B per lane (wave-uniform LDS base + lane*16)
__device__ __forceinline__ void gl_lds16(const void* gsrc, void* ldst) {
    typedef const __attribute__((address_space(1))) unsigned int GU;
    typedef __attribute__((address_space(3))) unsigned int LU;
    __builtin_amdgcn_global_load_lds((GU*)gsrc, (LU*)ldst, 16, 0, 0);
}

// ---------------- W prep: bf16 fragment-order layout + wnorm (f32+f64) ----
__global__ __launch_bounds__(256) void wprep(const float* __restrict__ Wm,
                                             unsigned short* __restrict__ Wb,
                                             float* __restrict__ wnorm,
                                             double* __restrict__ wnormd,
                                             float* __restrict__ enc_sum)
{
    const int r = blockIdx.x * 4 + (threadIdx.x >> 6);
    const int lane = threadIdx.x & 63;
    float4 v = ((const float4*)(Wm + (size_t)r * 256))[lane];
    ushort4 o;
    o.x = f2bf(v.x); o.y = f2bf(v.y); o.z = f2bf(v.z); o.w = f2bf(v.w);
    const int d0 = lane * 4;
    const int kk = d0 >> 5, quad = (d0 >> 3) & 3, jb = d0 & 7;
    const int tt = r >> 4, col = r & 15;
    const size_t idx = (size_t)tt * 4096 + (size_t)((kk * 4 + quad) * 16 + col) * 8 + jb;
    *(ushort4*)(Wb + idx) = o;
    double s = (double)v.x*(double)v.x + (double)v.y*(double)v.y
             + (double)v.z*(double)v.z + (double)v.w*(double)v.w;
    #pragma unroll
    for (int off = 32; off > 0; off >>= 1) s += __shfl_down(s, off);
    if (lane == 0) { wnormd[r] = s; wnorm[r] = (float)s; }
    if (blockIdx.x == 0) {
        #pragma unroll
        for (int q = 0; q < 4; ++q) enc_sum[threadIdx.x * 4 + q] = 0.0f;
    }
}

// ---------------- fused MFMA GEMM + top-k + fp64 refine + enc + quantize + loss ----
// 256 thr = 4 waves, 32 rows/block, grid 1024, LDS 36 KB -> 4 blocks/CU.
// Mappings:
//   MFMA:   wave w: g=w&1 (16-row group), h=w>>1 (512-code half); lane: col,quad
//   refine: row = t>>3 (0..31), q8 = t&7; thread owns dims c*32 + q8*4 + k.
// x ingestion: two-pass coalesced f32 LDS bounce (SWZW swizzle, 2-way writes).
// Main loop (32 iters): dbuf 2x16KB via global_load_lds; split 4+4 MFMA
// chains; med3 exact top-3 insert; in-loop enc row zero-streaming.
// Quantize: single pass, qtile [32 hw][stride 257] — 257 mod 32 = 1 makes
// BOTH the scalar writes (row + 4*q8 + k) and the transposed scalar reads
// (4*hq + j + cl) ~2-way (free). qtile ends @32888 < 33792 (small arrays).
__global__ __launch_bounds__(256, 4) void gemm_topk_quant(
    const float* __restrict__ x, const unsigned short* __restrict__ Wb,
    const float* __restrict__ wnorm, const double* __restrict__ wnd,
    const float* __restrict__ Wm,
    float* __restrict__ enc_sum,
    float* __restrict__ enc,
    float* __restrict__ outq, float* __restrict__ loss_part)
{
    __shared__ __align__(16) char lds[36864];
    // loop: buf0 = lds[0,16K), buf1 = lds[16K,32K); wnLds @ 32K (4 KB)
    // post-loop aliases (phases separated by barriers):
    float*  sCd   = (float*)lds;                 // [96][34] f32 = 13056 B (dump->merge)
    int*    mIdx  = (int*)(lds + 13312);         // [256] -> 14336
    double* rd    = (double*)(lds + 14336);      // [256] f64 -> 16384
    float*  qtile = (float*)lds;                 // [32][257] f32 = 32888 B (epilogue)
    // small arrays live past qtile (wnLds region, dead post-loop):
    double* rnr   = (double*)(lds + 33792);      // [32] f64 -> 34048
    int*    s0    = (int*)(lds + 34048);         // [32] -> 34176
    int*    s1    = (int*)(lds + 34176);         // [32] -> 34304
    float*  sw0   = (float*)(lds + 34304);       // [32] -> 34432
    float*  sw1   = (float*)(lds + 34432);       // [32] -> 34560
    double* sredd = (double*)(lds + 34560);      // [4]  -> 34592
    float*  xbounce = (float*)(lds + 16384);     // [32][128] f32 swizzled, pre-loop (buf1)
    float*  wnLds = (float*)(lds + 32768);       // [1024] f32 (loop only)

    const int t    = threadIdx.x;
    const int wave = t >> 6;
    const int g    = wave & 1;
    const int h    = wave >> 1;
    const int lane = t & 63;
    const int col  = lane & 15;
    const int quad = lane >> 4;
    const int r0   = blockIdx.x * 32;
    const int b    = r0 >> 10;
    const int hw0  = r0 & 1023;
    const float* xblk = x + (size_t)b * 262144 + hw0;   // + d*1024 + hw_local

    const int row = t >> 3;   // refine/epilogue row (hw local), 0..31
    const int q8  = t & 7;    // dim-slice

    // ---- issue prologue B staging (cc=0 -> buf0) + wnorm -> wnLds first ----
    const char* wb_bytes = (const char*)Wb;
    {
        const char* src = wb_bytes + (size_t)(h * 32) * 8192 + g * 4096;
        char* dstl = lds + h * 8192 + g * 4096;
        #pragma unroll
        for (int q = 0; q < 4; ++q)
            gl_lds16(src + q * 1024 + lane * 16, dstl + q * 1024);
        gl_lds16((const char*)wnorm + wave * 1024 + lane * 16,
                 (char*)wnLds + wave * 1024);
    }

    // ---- x ingestion: two-pass coalesced bounce through LDS ----
    float xs[32];
    short8 af[8];
    const int hwq   = t & 7;       // hw chunk (load mapping)
    const int dbase = t >> 3;      // 0..31   (load mapping)
    const int arow  = g * 16 + col;
    #pragma unroll
    for (int h2 = 0; h2 < 2; ++h2) {
        // coalesced global loads: 8 segments of 128B per wave-instr
        float4 xv0, xv1, xv2, xv3;
        {
            const float* xp = xblk + hwq * 4;
            xv0 = *(const float4*)(xp + (size_t)(h2 * 128 +  0 + dbase) * 1024);
            xv1 = *(const float4*)(xp + (size_t)(h2 * 128 + 32 + dbase) * 1024);
            xv2 = *(const float4*)(xp + (size_t)(h2 * 128 + 64 + dbase) * 1024);
            xv3 = *(const float4*)(xp + (size_t)(h2 * 128 + 96 + dbase) * 1024);
        }
        if (h2) __syncthreads();   // pass-0 readers done before overwrite
        // scatter to LDS [hw][dloc], SWZW word-XOR (2-way, free)
        #pragma unroll
        for (int rr = 0; rr < 4; ++rr) {
            const float4 xv = (rr == 0) ? xv0 : (rr == 1) ? xv1 : (rr == 2) ? xv2 : xv3;
            const int dloc = rr * 32 + dbase;
            #pragma unroll
            for (int j = 0; j < 4; ++j) {
                const int hw = hwq * 4 + j;
                const float vj = (j == 0) ? xv.x : (j == 1) ? xv.y : (j == 2) ? xv.z : xv.w;
                xbounce[(hw * 128 + dloc) ^ SWZW(hw)] = vj;
            }
        }
        __syncthreads();
        // xs: 4 b128 reads (dims c*32 + q8*4 .. +3)
        #pragma unroll
        for (int c2 = 0; c2 < 4; ++c2) {
            const int w = (row * 128 + c2 * 32 + q8 * 4) ^ SWZW(row);
            f32x4 v = *(const f32x4*)(xbounce + w);
            xs[(h2 * 4 + c2) * 4 + 0] = v.x;
            xs[(h2 * 4 + c2) * 4 + 1] = v.y;
            xs[(h2 * 4 + c2) * 4 + 2] = v.z;
            xs[(h2 * 4 + c2) * 4 + 3] = v.w;
        }
        // af: direct f32 -> bf16 fragments (rows g*16..g*16+15)
        #pragma unroll
        for (int kk2 = 0; kk2 < 4; ++kk2) {
            const int dloc = kk2 * 32 + quad * 8;
            const int wA = (arow * 128 + dloc) ^ SWZW(arow);
            const int wB = (arow * 128 + dloc + 4) ^ SWZW(arow);
            f32x4 u = *(const f32x4*)(xbounce + wA);
            f32x4 v = *(const f32x4*)(xbounce + wB);
            short8 f;
            f[0] = (short)f2bf(u.x); f[1] = (short)f2bf(u.y);
            f[2] = (short)f2bf(u.z); f[3] = (short)f2bf(u.w);
            f[4] = (short)f2bf(v.x); f[5] = (short)f2bf(v.y);
            f[6] = (short)f2bf(v.z); f[7] = (short)f2bf(v.w);
            af[h2 * 4 + kk2] = f;
        }
    }
    __syncthreads();   // pass-1 reads done; buf0+wnLds staged; cc=0 may write buf1

    float m0[4], m1[4], m2[4];
    #pragma unroll
    for (int r = 0; r < 4; ++r) { m0[r] = 3.4e38f; m1[r] = 3.4e38f; m2[r] = 3.4e38f; }

    const f32x4 zero4 = {0.f, 0.f, 0.f, 0.f};
    for (int cc = 0; cc < 32; ++cc) {
        if (cc < 31) {
            const char* src = wb_bytes + (size_t)(h * 32 + cc + 1) * 8192 + g * 4096;
            char* dstl = lds + ((cc + 1) & 1) * 16384 + h * 8192 + g * 4096;
            #pragma unroll
            for (int q = 0; q < 4; ++q)
                gl_lds16(src + q * 1024 + lane * 16, dstl + q * 1024);
        }
        // zero-stream one encodings row per iteration (coalesced 4 KB)
        *(f32x4*)(enc + (size_t)(r0 + cc) * KCODES + t * 4) = zero4;

        const char* bb = lds + (cc & 1) * 16384 + h * 8192;
        f32x4 acc_a = {0.f, 0.f, 0.f, 0.f};
        f32x4 acc_b = {0.f, 0.f, 0.f, 0.f};
        #pragma unroll
        for (int kk = 0; kk < 4; ++kk) {
            short8 b0 = *(const short8*)(bb + kk * 1024 + lane * 16);
            short8 b1 = *(const short8*)(bb + (kk + 4) * 1024 + lane * 16);
            acc_a = __builtin_amdgcn_mfma_f32_16x16x32_bf16(af[kk], b0, acc_a, 0, 0, 0);
            acc_b = __builtin_amdgcn_mfma_f32_16x16x32_bf16(af[kk + 4], b1, acc_b, 0, 0, 0);
        }
        const int code0 = h * 512 + cc * 16 + col;
        const float wn0 = wnLds[code0];
        #pragma unroll
        for (int r = 0; r < 4; ++r) {
            float pv0 = packdi(fmaf(-2.0f, acc_a[r] + acc_b[r], wn0), code0);
            // exact sorted-3 insert via med3 (3 ops)
            m2[r] = __builtin_amdgcn_fmed3f(m1[r], m2[r], pv0);
            m1[r] = __builtin_amdgcn_fmed3f(m0[r], m1[r], pv0);
            m0[r] = fminf(m0[r], pv0);
        }
        __syncthreads();   // staged data for cc+1 visible; buf[cc&1] reads done
    }

    // ---- dump per-lane candidates, transposed layout [96 slots][34 rows] ----
    #pragma unroll
    for (int r = 0; r < 4; ++r) {
        const int rl = g * 16 + quad * 4 + r;
        const int s  = h * 48 + col * 3;
        sCd[(s + 0) * 34 + rl] = m0[r];
        sCd[(s + 1) * 34 + rl] = m1[r];
        sCd[(s + 2) * 34 + rl] = m2[r];
    }
    __syncthreads();

    // ---- parallel exact top-8 merge: 8 threads/row, 12 slots each ----
    {
        float a0 = 3.4e38f, a1 = 3.4e38f, a2 = 3.4e38f, a3 = 3.4e38f,
              a4 = 3.4e38f, a5 = 3.4e38f, a6 = 3.4e38f, a7 = 3.4e38f;
        #pragma unroll
        for (int i = 0; i < 12; ++i) {
            float d = sCd[(q8 * 12 + i) * 34 + row];
            if (d < a7) {
                a7 = d; float tf;
                if (a7 < a6) { tf = a7; a7 = a6; a6 = tf; }
                if (a6 < a5) { tf = a6; a6 = a5; a5 = tf; }
                if (a5 < a4) { tf = a5; a5 = a4; a4 = tf; }
                if (a4 < a3) { tf = a4; a4 = a3; a3 = tf; }
                if (a3 < a2) { tf = a3; a3 = a2; a2 = tf; }
                if (a2 < a1) { tf = a2; a2 = a1; a1 = tf; }
                if (a1 < a0) { tf = a1; a1 = a0; a0 = tf; }
            }
        }
        // 8 rounds: global min of the 8 heads (values unique via packed code bits)
        float sel = 3.4e38f;
        #pragma unroll
        for (int q = 0; q < 8; ++q) {
            float m = a0;
            m = fminf(m, __shfl_xor(m, 1));
            m = fminf(m, __shfl_xor(m, 2));
            m = fminf(m, __shfl_xor(m, 4));
            if (q8 == q) sel = m;
            if (a0 == m) { a0 = a1; a1 = a2; a2 = a3; a3 = a4;
                           a4 = a5; a5 = a6; a6 = a7; a7 = 3.4e38f; }
        }
        mIdx[row * 8 + q8] = (int)(__float_as_uint(sel) & 1023u);
    }
    __syncthreads();

    // ---- fp64 refine from xs regs: coalesced 128B W reads per row-octet ----
    {
        int cd[8];
        #pragma unroll
        for (int c8 = 0; c8 < 8; ++c8) cd[c8] = mIdx[row * 8 + c8];
        double dot[8];
        #pragma unroll
        for (int c8 = 0; c8 < 8; ++c8) dot[c8] = 0.0;
        double rn = 0.0;
        #pragma unroll
        for (int c = 0; c < 8; ++c) {
            const int d0 = c * 32 + q8 * 4;
            const double x0 = (double)xs[c * 4 + 0];
            const double x1 = (double)xs[c * 4 + 1];
            const double x2 = (double)xs[c * 4 + 2];
            const double x3 = (double)xs[c * 4 + 3];
            rn += x0*x0 + x1*x1 + x2*x2 + x3*x3;
            #pragma unroll
            for (int c8 = 0; c8 < 8; ++c8) {
                const float4 wv = *(const float4*)(Wm + (size_t)cd[c8] * 256 + d0);
                dot[c8] += x0 * (double)wv.x + x1 * (double)wv.y
                         + x2 * (double)wv.z + x3 * (double)wv.w;
            }
        }
        #pragma unroll
        for (int m = 1; m < 8; m <<= 1) {
            #pragma unroll
            for (int c8 = 0; c8 < 8; ++c8) dot[c8] += __shfl_xor(dot[c8], m);
            rn += __shfl_xor(rn, m);
        }
        // static select of this thread's candidate (avoid dynamic reg indexing)
        int myc = 0; double mydot = 0.0;
        #pragma unroll
        for (int c8 = 0; c8 < 8; ++c8)
            if (q8 == c8) { myc = cd[c8]; mydot = dot[c8]; }
        rd[row * 8 + q8] = wnd[myc] - 2.0 * mydot;
        if (q8 == 0) rnr[row] = rn;
    }
    __syncthreads();

    // ---- final per-row top-2 (exact), weights + enc patch stores ----
    if (t < 32) {
        double rn = rnr[t];
        double d0 = 1e300, d1 = 1e300; int b0 = 1 << 30, b1 = 1 << 30;
        #pragma unroll
        for (int q = 0; q < 8; ++q) {
            double d = rd[t * 8 + q];
            int    c = mIdx[t * 8 + q];
            if (d < d0 || (d == d0 && c < b0)) { d1 = d0; b1 = b0; d0 = d; b0 = c; }
            else if (d < d1 || (d == d1 && c < b1)) { d1 = d; b1 = c; }
        }
        double D0 = rn + d0;
        double D1 = rn + d1;
        double inv0 = 1.0 / D0, inv1 = 1.0 / D1;
        double nrm = sqrt(inv0 * inv0 + inv1 * inv1);
        if (nrm < 1e-12) nrm = 1e-12;
        float w0 = (float)(inv0 / nrm);
        float w1 = (float)(inv1 / nrm);
        s0[t] = b0; s1[t] = b1; sw0[t] = w0; sw1[t] = w1;
        atomicAdd(&enc_sum[b0], w0);
        atomicAdd(&enc_sum[b1], w1);
        // patch the two weights into the pre-zeroed encodings row.
        enc[(size_t)(r0 + t) * KCODES + b0] = w0;
        enc[(size_t)(r0 + t) * KCODES + b1] = w1;
    }
    __syncthreads();

    // ---- quantize + loss (from xs) + NCHW write, single full-width pass ----
    double ls = 0.0;
    {
        const int   cA = s0[row], cB = s1[row];
        const float w0 = sw0[row], w1 = sw1[row];
        #pragma unroll
        for (int c = 0; c < 8; ++c) {
            const int dg = c * 32 + q8 * 4;
            const float4 a  = *(const float4*)(Wm + (size_t)cA * 256 + dg);
            const float4 bv = *(const float4*)(Wm + (size_t)cB * 256 + dg);
            float q0 = w0 * a.x + w1 * bv.x;
            float q1 = w0 * a.y + w1 * bv.y;
            float q2 = w0 * a.z + w1 * bv.z;
            float q3 = w0 * a.w + w1 * bv.w;
            float e0 = q0 - xs[c * 4 + 0];
            float e1 = q1 - xs[c * 4 + 1];
            float e2 = q2 - xs[c * 4 + 2];
            float e3 = q3 - xs[c * 4 + 3];
            ls += (double)(e0*e0 + e1*e1 + e2*e2 + e3*e3);
            float* qp = qtile + row * 257 + dg;   // scalar stores: ~2-way, free
            qp[0] = q0; qp[1] = q1; qp[2] = q2; qp[3] = q3;
        }
    }
    __syncthreads();
    #pragma unroll
    for (int p = 0; p < 8; ++p) {
        const int task = p * 256 + t;
        const int cl   = task >> 3;       // channel 0..255
        const int hq   = task & 7;
        f32x4 v;
        v.x = qtile[(hq * 4 + 0) * 257 + cl];
        v.y = qtile[(hq * 4 + 1) * 257 + cl];
        v.z = qtile[(hq * 4 + 2) * 257 + cl];
        v.w = qtile[(hq * 4 + 3) * 257 + cl];
        *(f32x4*)(outq + ((size_t)(b * 256 + cl)) * 1024 + hw0 + hq * 4) = v;
    }

    // ---- block loss partial ----
    #pragma unroll
    for (int off = 32; off > 0; off >>= 1) ls += __shfl_down(ls, off);
    if (lane == 0) sredd[wave] = ls;
    __syncthreads();
    if (t == 0) {
        double s = 0.0;
        #pragma unroll
        for (int w = 0; w < 4; ++w) s += sredd[w];
        loss_part[blockIdx.x] = (float)s;
    }
}

// ---------------- finalize: loss + perplexity ----------------
__global__ __launch_bounds__(256) void finalize_k(const float* __restrict__ enc_sum,
                                                  const float* __restrict__ loss_part,
                                                  float* __restrict__ out)
{
    __shared__ double sh[256];
    const int t = threadIdx.x;
    double ls = 0.0;
    for (int i = t; i < 1024; i += 256) ls += (double)loss_part[i];
    sh[t] = ls; __syncthreads();
    for (int s = 128; s > 0; s >>= 1) { if (t < s) sh[t] += sh[t + s]; __syncthreads(); }
    double loss_sum = sh[0];
    __syncthreads();
    double ps = 0.0;
    for (int k = t; k < KCODES; k += 256) {
        double p = (double)enc_sum[k] / (double)NROWS;
        ps += p * log(p + 1e-10);
    }
    sh[t] = ps; __syncthreads();
    for (int s = 128; s > 0; s >>= 1) { if (t < s) sh[t] += sh[t + s]; __syncthreads(); }
    if (t == 0) {
        out[0]        = (float)(1.25 * loss_sum / 8388608.0);
        out[OUT_PERP] = (float)exp(-sh[0]);
    }
}

extern "C" void kernel_launch(void* const* d_in, const int* in_sizes, int n_in,
                              void* d_out, int out_size, void* d_ws, size_t ws_size,
                              hipStream_t stream)
{
    const float* x  = (const float*)d_in[0];
    const float* Wm = (const float*)d_in[1];
    float* out = (float*)d_out;
    float* ws  = (float*)d_ws;

    unsigned short* Wb      = (unsigned short*)(ws + OFF_WB);
    float*          wnorm   = ws + OFF_WNORM;
    float*          enc_sum = ws + OFF_ENCSUM;
    float*          loss_p  = ws + OFF_LOSSP;
    double*         wnd     = (double*)(ws + OFF_WND);

    wprep<<<KCODES / 4, 256, 0, stream>>>(Wm, Wb, wnorm, wnd, enc_sum);
    gemm_topk_quant<<<NROWS / 32, 256, 0, stream>>>(x, Wb, wnorm, wnd, Wm, enc_sum,
                                                    out + OUT_ENC, out + OUT_Q, loss_p);
    finalize_k<<<1, 256, 0, stream>>>(enc_sum, loss_p, out);
}